// Round 5
// baseline (227.288 us; speedup 1.0000x reference)
//
#include <hip/hip_runtime.h>

// x(8,64,8,64,64) fp32, w_q(32,64), w_kv(64,64)
// f = d*8+n (256), p = y*64+xi (4096), p2 = y2*32+x2 (1024)

typedef __attribute__((ext_vector_type(8))) short short8;
typedef __attribute__((ext_vector_type(4))) float floatx4;
typedef __attribute__((ext_vector_type(2))) unsigned uintx2;

__device__ __forceinline__ short f2bf(float f) {  // RNE, finite only
    unsigned u = __builtin_bit_cast(unsigned, f);
    u += 0x7fffu + ((u >> 16) & 1u);
    return (short)(u >> 16);
}
__device__ __forceinline__ unsigned pack2bf(float a, float b) {
    return (unsigned)(unsigned short)f2bf(a) | ((unsigned)(unsigned short)f2bf(b) << 16);
}

// ---------------- Fused projection: q (normalized), k (normalized), v ----------------
// (unchanged from R4 — validated)
__global__ __launch_bounds__(256) void proj(const float* __restrict__ x,
                                            const float* __restrict__ wq,
                                            const float* __restrict__ wkv,
                                            short* __restrict__ qraw,
                                            short* __restrict__ kraw,
                                            short* __restrict__ vraw) {
    int b = blockIdx.x >> 6, y = blockIdx.x & 63;
    int t = threadIdx.x;
    int n = t >> 5, dg = (t >> 3) & 3, xc = t & 7;
    bool kv = (y & 1) == 0;
    int y2 = y >> 1;

    __shared__ __align__(16) float wq_s[64 * 32];   // [c][d]
    __shared__ __align__(16) float wkv_s[64 * 64];  // [c][e]
    __shared__ __align__(16) float xs[128 * 36];    // [c16*n8][32xi + pad]; overlaid by q_lds
    __shared__ __align__(16) short k_lds[16 * 264];
    __shared__ __align__(16) short v_lds[256 * 16]; // [f][xi2]
    __shared__ float red[32 * 33];
    __shared__ float nrm[32];
    short* q_lds = (short*)xs;                      // 16896 B <= 18432 B

    for (int i = t; i < 2048; i += 256) { int d = i >> 6, c = i & 63; wq_s[c * 32 + d] = wq[i]; }
    for (int i = t; i < 4096; i += 256) { int e = i >> 6, c = i & 63; wkv_s[c * 64 + e] = wkv[i]; }
    const float* xb = x + (size_t)b * 2097152 + y * 64;   // batch stride c*n*h*w

    for (int xh = 0; xh < 2; ++xh) {
        float qa[8][4], ka[8][2], va[8][2];
#pragma unroll
        for (int j = 0; j < 8; ++j) {
            qa[j][0] = qa[j][1] = qa[j][2] = qa[j][3] = 0.f;
            ka[j][0] = ka[j][1] = 0.f; va[j][0] = va[j][1] = 0.f;
        }
        for (int cc = 0; cc < 4; ++cc) {
            __syncthreads();
#pragma unroll
            for (int it = 0; it < 4; ++it) {
                int i = it * 256 + t, cn = i >> 3, e = i & 7;
                float4 v = *(const float4*)(xb + (size_t)(cc * 16 + (cn >> 3)) * 32768 + (cn & 7) * 4096 + xh * 32 + e * 4);
                *(float4*)(xs + cn * 36 + e * 4) = v;
            }
            __syncthreads();
            for (int c = 0; c < 16; ++c) {
                float4 xv = *(const float4*)(xs + (c * 8 + n) * 36 + xc * 4);
                float xw[4] = {xv.x, xv.y, xv.z, xv.w};
                int cg = cc * 16 + c;
                float4 wqa = *(const float4*)(wq_s + cg * 32 + dg * 8);
                float4 wqb = *(const float4*)(wq_s + cg * 32 + dg * 8 + 4);
                float wj[8] = {wqa.x, wqa.y, wqa.z, wqa.w, wqb.x, wqb.y, wqb.z, wqb.w};
#pragma unroll
                for (int j = 0; j < 8; ++j)
#pragma unroll
                    for (int i2 = 0; i2 < 4; ++i2) qa[j][i2] += wj[j] * xw[i2];
                if (kv) {
                    float4 wka = *(const float4*)(wkv_s + cg * 64 + dg * 8);
                    float4 wkb = *(const float4*)(wkv_s + cg * 64 + dg * 8 + 4);
                    float4 wva = *(const float4*)(wkv_s + cg * 64 + 32 + dg * 8);
                    float4 wvb = *(const float4*)(wkv_s + cg * 64 + 32 + dg * 8 + 4);
                    float wk[8] = {wka.x, wka.y, wka.z, wka.w, wkb.x, wkb.y, wkb.z, wkb.w};
                    float wv2[8] = {wva.x, wva.y, wva.z, wva.w, wvb.x, wvb.y, wvb.z, wvb.w};
#pragma unroll
                    for (int j = 0; j < 8; ++j) {
                        ka[j][0] += wk[j] * xw[0]; ka[j][1] += wk[j] * xw[2];
                        va[j][0] += wv2[j] * xw[0]; va[j][1] += wv2[j] * xw[2];
                    }
                }
            }
        }
        __syncthreads();
#pragma unroll
        for (int i2 = 0; i2 < 4; ++i2) {
            float s = 0.f;
#pragma unroll
            for (int j = 0; j < 8; ++j) s += qa[j][i2] * qa[j][i2];
            red[(xc * 4 + i2) * 33 + n * 4 + dg] = s;
        }
        __syncthreads();
        if (t < 32) {
            float s = 0.f;
            for (int k = 0; k < 32; ++k) s += red[t * 33 + k];
            nrm[t] = 1.f / fmaxf(sqrtf(s), 1e-12f);
        }
        __syncthreads();
#pragma unroll
        for (int i2 = 0; i2 < 4; ++i2) {
            float sc = nrm[xc * 4 + i2];
#pragma unroll
            for (int j = 0; j < 8; ++j)
                q_lds[(xc * 4 + i2) * 264 + (dg * 8 + j) * 8 + n] = f2bf(qa[j][i2] * sc);
        }
        __syncthreads();
        {
            size_t qg = ((size_t)b * 4096 + y * 64 + xh * 32) * 256;
#pragma unroll
            for (int it = 0; it < 4; ++it) {
                int r = it * 8 + (t >> 5), sg = t & 31;
                *(uint4*)(qraw + qg + (size_t)r * 256 + sg * 8) = *(const uint4*)(q_lds + r * 264 + sg * 8);
            }
        }
        if (kv) {
            __syncthreads();
#pragma unroll
            for (int ii = 0; ii < 2; ++ii) {
                float s = 0.f;
#pragma unroll
                for (int j = 0; j < 8; ++j) s += ka[j][ii] * ka[j][ii];
                red[(xc * 2 + ii) * 33 + n * 4 + dg] = s;
            }
            __syncthreads();
            if (t < 16) {
                float s = 0.f;
                for (int k = 0; k < 32; ++k) s += red[t * 33 + k];
                nrm[t] = 1.f / fmaxf(sqrtf(s), 1e-12f);
            }
            __syncthreads();
#pragma unroll
            for (int ii = 0; ii < 2; ++ii) {
                float sc = nrm[xc * 2 + ii];
#pragma unroll
                for (int j = 0; j < 8; ++j) {
                    int f = (dg * 8 + j) * 8 + n;
                    k_lds[(xc * 2 + ii) * 264 + f] = f2bf(ka[j][ii] * sc);
                    v_lds[f * 16 + xc * 2 + ii] = f2bf(va[j][ii]);
                }
            }
            __syncthreads();
            size_t kg = ((size_t)b * 1024 + y2 * 32 + xh * 16) * 256;
#pragma unroll
            for (int it = 0; it < 2; ++it) {
                int r = it * 8 + (t >> 5), sg = t & 31;
                *(uint4*)(kraw + kg + (size_t)r * 256 + sg * 8) = *(const uint4*)(k_lds + r * 264 + sg * 8);
            }
            size_t vg = (size_t)b * 262144 + (size_t)y2 * 32 + xh * 16;
#pragma unroll
            for (int it = 0; it < 2; ++it) {
                int idx = it * 256 + t, f = idx >> 1, hh = idx & 1;
                *(uint4*)(vraw + vg + (size_t)f * 1024 + hh * 8) = *(const uint4*)(v_lds + f * 16 + hh * 8);
            }
        }
    }
}

// ---- attn: 512 threads = 2 groups x 4 waves; group g owns kv-chunks [g*16, g*16+16) ----
// grid 256 = (b, qt of 128 rows). Per-group LDS: k_s single 16896 + v_s dbuf 40960 + p_s 10240 = 68096 B.
// Epilogue: group1 acc -> LDS (overlay) -> group0 sums, normalizes with dsum[0]+dsum[1], stores.
__global__ __launch_bounds__(512, 2) void attn(const short* __restrict__ qraw,
                                               const short* __restrict__ kraw,
                                               const short* __restrict__ vraw,
                                               float* __restrict__ out) {
    int b = blockIdx.x >> 5, qt = blockIdx.x & 31;
    int t = threadIdx.x;
    int w = t >> 6, g = w >> 2, wv = w & 3;
    int lane = t & 63, l16 = lane & 15, quad = lane >> 4;
    int tl = t & 255;                               // thread index within group

    __shared__ __align__(16) char smem[136192];     // 2 x 68096
    __shared__ float dsum[2][128];
    short* k_s = (short*)(smem + g * 68096);                    // [32][264]
    short* v_sA = (short*)(smem + g * 68096 + 16896);           // [2][256*40]
    short* p_s = (short*)(smem + g * 68096 + 16896 + 40960);    // [128][40]
    float* ebuf = (float*)smem;                                  // epilogue overlay [128][260]

    // Q fragments (prenormalized): wave owns p = qt*128 + wv*32 + pt*16 + l16 (same for both groups)
    short8 qf[2][8];
    const short* qb = qraw + ((size_t)b * 4096 + qt * 128 + wv * 32) * 256;
#pragma unroll
    for (int pt = 0; pt < 2; ++pt)
#pragma unroll
        for (int fs = 0; fs < 8; ++fs)
            qf[pt][fs] = *(const short8*)(qb + (pt * 16 + l16) * 256 + fs * 32 + quad * 8);

    floatx4 acc[8][4];  // [p-tile of 16][f-tile of 16 within wave's 64-f slice]
#pragma unroll
    for (int i = 0; i < 8; ++i)
#pragma unroll
        for (int j = 0; j < 4; ++j) acc[i][j] = (floatx4){0.f, 0.f, 0.f, 0.f};
    float dacc0 = 0.f, dacc1 = 0.f;

    int krow = tl >> 3, kseg = tl & 7;
    const short* kbase = kraw + ((size_t)b * 1024 + g * 512 + krow) * 256 + kseg * 32;
    const short* vbase = vraw + ((size_t)b * 256 + tl) * 1024 + g * 512;

    short8 kst[4], vst[4];
    // stage group-chunk 0 into k_s / v_sA[0]
#pragma unroll
    for (int j = 0; j < 4; ++j) {
        kst[j] = *(const short8*)(kbase + j * 8);
        vst[j] = *(const short8*)(vbase + j * 8);
    }
#pragma unroll
    for (int j = 0; j < 4; ++j) {
        *(short8*)(k_s + krow * 264 + kseg * 32 + j * 8) = kst[j];
        *(short8*)(v_sA + tl * 40 + j * 8) = vst[j];
    }
    // prefetch group-chunk 1 into regs
#pragma unroll
    for (int j = 0; j < 4; ++j) {
        kst[j] = *(const short8*)(kbase + (size_t)32 * 256 + j * 8);
        vst[j] = *(const short8*)(vbase + 32 + j * 8);
    }
    __syncthreads();

    for (int i = 0; i < 16; ++i) {                  // group-local chunk index
        short* v_cur = v_sA + (i & 1) * (256 * 40);
        short* v_nxt = v_sA + ((i & 1) ^ 1) * (256 * 40);
        // phase 1: S^T[kp][p] for wave's 32 p
        floatx4 cc0[2] = {(floatx4){0.f,0.f,0.f,0.f}, (floatx4){0.f,0.f,0.f,0.f}};
        floatx4 cc1[2] = {(floatx4){0.f,0.f,0.f,0.f}, (floatx4){0.f,0.f,0.f,0.f}};
#pragma unroll
        for (int kt = 0; kt < 2; ++kt) {
#pragma unroll
            for (int fs = 0; fs < 8; ++fs) {
                short8 a = *(const short8*)(k_s + (kt * 16 + l16) * 264 + fs * 32 + quad * 8);
                cc0[kt] = __builtin_amdgcn_mfma_f32_16x16x32_bf16(a, qf[0][fs], cc0[kt], 0, 0, 0);
                cc1[kt] = __builtin_amdgcn_mfma_f32_16x16x32_bf16(a, qf[1][fs], cc1[kt], 0, 0, 0);
            }
        }
        // |s|<=1: plain exp; stash P (one b64 per kt per q-set)
#pragma unroll
        for (int kt = 0; kt < 2; ++kt) {
            float e0 = __expf(cc0[kt][0]), e1 = __expf(cc0[kt][1]);
            float e2 = __expf(cc0[kt][2]), e3 = __expf(cc0[kt][3]);
            dacc0 += (e0 + e1) + (e2 + e3);
            uintx2 w0; w0[0] = pack2bf(e0, e1); w0[1] = pack2bf(e2, e3);
            *(uintx2*)(p_s + (wv * 32 + l16) * 40 + kt * 16 + quad * 4) = w0;
            float f0 = __expf(cc1[kt][0]), f1 = __expf(cc1[kt][1]);
            float f2 = __expf(cc1[kt][2]), f3 = __expf(cc1[kt][3]);
            dacc1 += (f0 + f1) + (f2 + f3);
            uintx2 w1; w1[0] = pack2bf(f0, f1); w1[1] = pack2bf(f2, f3);
            *(uintx2*)(p_s + (wv * 32 + 16 + l16) * 40 + kt * 16 + quad * 4) = w1;
        }
        __syncthreads();   // B1: P ready; phase-1 k_s reads done

        // commit prefetched chunk i+1 (k_s single buffer: safe — readers resume after B2)
        if (i < 15) {
#pragma unroll
            for (int j = 0; j < 4; ++j) {
                *(short8*)(k_s + krow * 264 + kseg * 32 + j * 8) = kst[j];
                *(short8*)(v_nxt + tl * 40 + j * 8) = vst[j];
            }
        }
        // phase 2: out^T[f][p] += V^T x P^T ; wave owns f slice [wv*64, +64), all 128 p
        short8 av[4];
#pragma unroll
        for (int fl = 0; fl < 4; ++fl)
            av[fl] = *(const short8*)(v_cur + (wv * 64 + fl * 16 + l16) * 40 + quad * 8);
#pragma unroll
        for (int p2 = 0; p2 < 8; ++p2) {
            short8 bq = *(const short8*)(p_s + (p2 * 16 + l16) * 40 + quad * 8);
#pragma unroll
            for (int fl = 0; fl < 4; ++fl)
                acc[p2][fl] = __builtin_amdgcn_mfma_f32_16x16x32_bf16(av[fl], bq, acc[p2][fl], 0, 0, 0);
        }
        // prefetch chunk i+2 into regs
        if (i < 14) {
            int kp0n = (i + 2) * 32;
#pragma unroll
            for (int j = 0; j < 4; ++j) {
                kst[j] = *(const short8*)(kbase + (size_t)kp0n * 256 + j * 8);
                vst[j] = *(const short8*)(vbase + kp0n + j * 8);
            }
        }
        __syncthreads();   // B2
    }

    // partial denominators (per group)
    dacc0 += __shfl_xor(dacc0, 16); dacc0 += __shfl_xor(dacc0, 32);
    dacc1 += __shfl_xor(dacc1, 16); dacc1 += __shfl_xor(dacc1, 32);
    if (quad == 0) {
        dsum[g][wv * 32 + l16] = dacc0;
        dsum[g][wv * 32 + 16 + l16] = dacc1;
    }
    __syncthreads();       // main-phase LDS reads done; dsum ready; ebuf overlay now safe

    // group 1 exports acc via LDS [p][260f-padded]
    if (g == 1) {
#pragma unroll
        for (int p2 = 0; p2 < 8; ++p2)
#pragma unroll
            for (int fl = 0; fl < 4; ++fl)
                *(floatx4*)(ebuf + (p2 * 16 + l16) * 260 + wv * 64 + fl * 16 + quad * 4) = acc[p2][fl];
    }
    __syncthreads();
    if (g == 0) {
        float* ob = out + (size_t)b * 1048576 + qt * 128;
#pragma unroll
        for (int p2 = 0; p2 < 8; ++p2) {
            float inv = 1.f / (dsum[0][p2 * 16 + l16] + dsum[1][p2 * 16 + l16]);
#pragma unroll
            for (int fl = 0; fl < 4; ++fl) {
                floatx4 o = *(const floatx4*)(ebuf + (p2 * 16 + l16) * 260 + wv * 64 + fl * 16 + quad * 4);
                o += acc[p2][fl];
                int f0 = wv * 64 + fl * 16 + quad * 4;
#pragma unroll
                for (int r = 0; r < 4; ++r)
                    ob[(size_t)(f0 + r) * 4096 + p2 * 16 + l16] = o[r] * inv;
            }
        }
    }
}

extern "C" void kernel_launch(void* const* d_in, const int* in_sizes, int n_in,
                              void* d_out, int out_size, void* d_ws, size_t ws_size,
                              hipStream_t stream) {
    (void)in_sizes; (void)n_in; (void)out_size; (void)ws_size;
    const float* x   = (const float*)d_in[0];
    const float* wqp = (const float*)d_in[1];
    const float* wkv = (const float*)d_in[2];
    float* out = (float*)d_out;

    char* ws = (char*)d_ws;
    short* qraw = (short*)ws;                          // 16 MiB, [b][p][f] normalized bf16
    short* kraw = (short*)(ws + 16777216);             // 4 MiB,  [b][p2][f] normalized bf16
    short* vraw = (short*)(ws + 16777216 + 4194304);   // 4 MiB,  [b][f][p2] bf16

    proj<<<512, 256, 0, stream>>>(x, wqp, wkv, qraw, kraw, vraw);
    attn<<<256, 512, 0, stream>>>(qraw, kraw, vraw, out);
}

// Round 6
// 203.497 us; speedup vs baseline: 1.1169x; 1.1169x over previous
//
#include <hip/hip_runtime.h>

// x(8,64,8,64,64) fp32, w_q(32,64), w_kv(64,64)
// f = d*8+n (256), p = y*64+xi (4096), p2 = y2*32+x2 (1024)

typedef __attribute__((ext_vector_type(8))) short short8;
typedef __attribute__((ext_vector_type(4))) float floatx4;
typedef __attribute__((ext_vector_type(2))) unsigned uintx2;

__device__ __forceinline__ short f2bf(float f) {  // RNE, finite only
    unsigned u = __builtin_bit_cast(unsigned, f);
    u += 0x7fffu + ((u >> 16) & 1u);
    return (short)(u >> 16);
}
__device__ __forceinline__ unsigned pack2bf(float a, float b) {
    return (unsigned)(unsigned short)f2bf(a) | ((unsigned)(unsigned short)f2bf(b) << 16);
}

// ---------------- Fused projection v2: q (normalized), k (normalized), v ----------------
// grid 512 = (b, y). Wave = dg (weights wave-uniform -> scalar s_load from K$, no LDS for w).
// Thread: dg = t>>6, n = (t>>3)&7, xc = t&7 (xi = xc*4+i2 within 32-half).
__global__ __launch_bounds__(256) void proj(const float* __restrict__ x,
                                            const float* __restrict__ wq,
                                            const float* __restrict__ wkv,
                                            short* __restrict__ qraw,
                                            short* __restrict__ kraw,
                                            short* __restrict__ vraw) {
    int b = blockIdx.x >> 6, y = blockIdx.x & 63;
    int t = threadIdx.x;
    int dg = __builtin_amdgcn_readfirstlane(t >> 6);   // wave-uniform -> SGPR
    int n = (t >> 3) & 7, xc = t & 7;
    bool kv = (y & 1) == 0;
    int y2 = y >> 1;

    __shared__ __align__(16) float xs[128 * 36];    // [c16*n8][32xi + pad]; overlaid by q_lds
    __shared__ __align__(16) short k_lds[16 * 264];
    __shared__ __align__(16) short v_lds[256 * 16]; // [f][xi2]
    __shared__ float red[32 * 33];
    __shared__ float nrm[32];
    short* q_lds = (short*)xs;                      // 16896 B <= 18432 B

    const float* xb = x + (size_t)b * 2097152 + y * 64;   // batch stride c*n*h*w

    for (int xh = 0; xh < 2; ++xh) {
        float qa[8][4], ka[8][2], va[8][2];
#pragma unroll
        for (int j = 0; j < 8; ++j) {
            qa[j][0] = qa[j][1] = qa[j][2] = qa[j][3] = 0.f;
            ka[j][0] = ka[j][1] = 0.f; va[j][0] = va[j][1] = 0.f;
        }
        for (int cc = 0; cc < 4; ++cc) {
            __syncthreads();
#pragma unroll
            for (int it = 0; it < 4; ++it) {
                int i = it * 256 + t, cn = i >> 3, e = i & 7;
                float4 v = *(const float4*)(xb + (size_t)(cc * 16 + (cn >> 3)) * 32768 + (cn & 7) * 4096 + xh * 32 + e * 4);
                *(float4*)(xs + cn * 36 + e * 4) = v;
            }
            __syncthreads();
#pragma unroll 4
            for (int c = 0; c < 16; ++c) {
                int cg = cc * 16 + c;
                float4 xv = *(const float4*)(xs + (c * 8 + n) * 36 + xc * 4);
                float xw[4] = {xv.x, xv.y, xv.z, xv.w};
#pragma unroll
                for (int j = 0; j < 8; ++j) {
                    float wj = wq[(dg * 8 + j) * 64 + cg];         // s_load (K$)
#pragma unroll
                    for (int i2 = 0; i2 < 4; ++i2) qa[j][i2] += wj * xw[i2];
                }
                if (kv) {
#pragma unroll
                    for (int j = 0; j < 8; ++j) {
                        float wk = wkv[(dg * 8 + j) * 64 + cg];        // s_load
                        float wv2 = wkv[(32 + dg * 8 + j) * 64 + cg];  // s_load
                        ka[j][0] += wk * xw[0]; ka[j][1] += wk * xw[2];
                        va[j][0] += wv2 * xw[0]; va[j][1] += wv2 * xw[2];
                    }
                }
            }
        }
        // ---- q: row-l2norm over f, write bf16 via LDS, coalesced flush ----
        __syncthreads();   // all reads of xs done (q_lds overlays xs)
#pragma unroll
        for (int i2 = 0; i2 < 4; ++i2) {
            float s = 0.f;
#pragma unroll
            for (int j = 0; j < 8; ++j) s += qa[j][i2] * qa[j][i2];
            red[(xc * 4 + i2) * 33 + n * 4 + dg] = s;
        }
        __syncthreads();
        if (t < 32) {
            float s = 0.f;
            for (int k = 0; k < 32; ++k) s += red[t * 33 + k];
            nrm[t] = 1.f / fmaxf(sqrtf(s), 1e-12f);
        }
        __syncthreads();
#pragma unroll
        for (int i2 = 0; i2 < 4; ++i2) {
            float sc = nrm[xc * 4 + i2];
#pragma unroll
            for (int j = 0; j < 8; ++j)
                q_lds[(xc * 4 + i2) * 264 + (dg * 8 + j) * 8 + n] = f2bf(qa[j][i2] * sc);
        }
        __syncthreads();
        {
            size_t qg = ((size_t)b * 4096 + y * 64 + xh * 32) * 256;
#pragma unroll
            for (int it = 0; it < 4; ++it) {
                int r = it * 8 + (t >> 5), sg = t & 31;
                *(uint4*)(qraw + qg + (size_t)r * 256 + sg * 8) = *(const uint4*)(q_lds + r * 264 + sg * 8);
            }
        }
        // ---- k (col-l2norm over f) and v ----
        if (kv) {
            __syncthreads();
#pragma unroll
            for (int ii = 0; ii < 2; ++ii) {
                float s = 0.f;
#pragma unroll
                for (int j = 0; j < 8; ++j) s += ka[j][ii] * ka[j][ii];
                red[(xc * 2 + ii) * 33 + n * 4 + dg] = s;
            }
            __syncthreads();
            if (t < 16) {
                float s = 0.f;
                for (int k = 0; k < 32; ++k) s += red[t * 33 + k];
                nrm[t] = 1.f / fmaxf(sqrtf(s), 1e-12f);
            }
            __syncthreads();
#pragma unroll
            for (int ii = 0; ii < 2; ++ii) {
                float sc = nrm[xc * 2 + ii];
#pragma unroll
                for (int j = 0; j < 8; ++j) {
                    int f = (dg * 8 + j) * 8 + n;
                    k_lds[(xc * 2 + ii) * 264 + f] = f2bf(ka[j][ii] * sc);
                    v_lds[f * 16 + xc * 2 + ii] = f2bf(va[j][ii]);
                }
            }
            __syncthreads();
            size_t kg = ((size_t)b * 1024 + y2 * 32 + xh * 16) * 256;
#pragma unroll
            for (int it = 0; it < 2; ++it) {
                int r = it * 8 + (t >> 5), sg = t & 31;
                *(uint4*)(kraw + kg + (size_t)r * 256 + sg * 8) = *(const uint4*)(k_lds + r * 264 + sg * 8);
            }
            size_t vg = (size_t)b * 262144 + (size_t)y2 * 32 + xh * 16;
#pragma unroll
            for (int it = 0; it < 2; ++it) {
                int idx = it * 256 + t, f = idx >> 1, hh = idx & 1;
                *(uint4*)(vraw + vg + (size_t)f * 1024 + hh * 8) = *(const uint4*)(v_lds + f * 16 + hh * 8);
            }
        }
    }
}

// ---------------- attn: R4 version (validated 65 us) — qtile=128, 4 waves, dbuf, 2 barriers/kc ----
// grid 256 = (b, qt of 128 rows), 256 threads
__global__ __launch_bounds__(256, 1) void attn(const short* __restrict__ qraw,
                                               const short* __restrict__ kraw,
                                               const short* __restrict__ vraw,
                                               float* __restrict__ out) {
    int b = blockIdx.x >> 5, qt = blockIdx.x & 31;
    int t = threadIdx.x, wv = t >> 6, lane = t & 63, l16 = lane & 15, quad = lane >> 4;

    __shared__ __align__(16) short k_s[2][32 * 264];  // [kp][f]+pad
    __shared__ __align__(16) short v_s[2][256 * 40];  // [f][kp]+pad
    __shared__ __align__(16) short p_s[2][128 * 40];  // [p][kp]+pad
    __shared__ float dsum[128];

    // Q fragments (prenormalized): wave owns p = qt*128 + wv*32 + pt*16 + l16
    short8 qf[2][8];
    const short* qb = qraw + ((size_t)b * 4096 + qt * 128 + wv * 32) * 256;
#pragma unroll
    for (int pt = 0; pt < 2; ++pt)
#pragma unroll
        for (int fs = 0; fs < 8; ++fs)
            qf[pt][fs] = *(const short8*)(qb + (pt * 16 + l16) * 256 + fs * 32 + quad * 8);

    floatx4 acc[8][4];  // [p-tile of 16][f-tile of 16 within wave's 64-f slice]
#pragma unroll
    for (int i = 0; i < 8; ++i)
#pragma unroll
        for (int j = 0; j < 4; ++j) acc[i][j] = (floatx4){0.f, 0.f, 0.f, 0.f};
    float dacc0 = 0.f, dacc1 = 0.f;

    int krow = t >> 3, kseg = t & 7;
    const short* kbase = kraw + ((size_t)b * 1024 + krow) * 256 + kseg * 32;
    const short* vbase = vraw + ((size_t)b * 256 + t) * 1024;

    short8 kst[4], vst[4];
#pragma unroll
    for (int j = 0; j < 4; ++j) {
        kst[j] = *(const short8*)(kbase + j * 8);
        vst[j] = *(const short8*)(vbase + j * 8);
    }
#pragma unroll
    for (int j = 0; j < 4; ++j) {
        *(short8*)(k_s[0] + krow * 264 + kseg * 32 + j * 8) = kst[j];
        *(short8*)(v_s[0] + t * 40 + j * 8) = vst[j];
    }
#pragma unroll
    for (int j = 0; j < 4; ++j) {
        kst[j] = *(const short8*)(kbase + (size_t)32 * 256 + j * 8);
        vst[j] = *(const short8*)(vbase + 32 + j * 8);
    }
    __syncthreads();

    for (int kc = 0; kc < 32; ++kc) {
        int cur = kc & 1, nxt = cur ^ 1;
        floatx4 cc0[2] = {(floatx4){0.f,0.f,0.f,0.f}, (floatx4){0.f,0.f,0.f,0.f}};
        floatx4 cc1[2] = {(floatx4){0.f,0.f,0.f,0.f}, (floatx4){0.f,0.f,0.f,0.f}};
#pragma unroll
        for (int kt = 0; kt < 2; ++kt) {
#pragma unroll
            for (int fs = 0; fs < 8; ++fs) {
                short8 a = *(const short8*)(k_s[cur] + (kt * 16 + l16) * 264 + fs * 32 + quad * 8);
                cc0[kt] = __builtin_amdgcn_mfma_f32_16x16x32_bf16(a, qf[0][fs], cc0[kt], 0, 0, 0);
                cc1[kt] = __builtin_amdgcn_mfma_f32_16x16x32_bf16(a, qf[1][fs], cc1[kt], 0, 0, 0);
            }
        }
#pragma unroll
        for (int kt = 0; kt < 2; ++kt) {
            float e0 = __expf(cc0[kt][0]), e1 = __expf(cc0[kt][1]);
            float e2 = __expf(cc0[kt][2]), e3 = __expf(cc0[kt][3]);
            dacc0 += (e0 + e1) + (e2 + e3);
            uintx2 w0; w0[0] = pack2bf(e0, e1); w0[1] = pack2bf(e2, e3);
            *(uintx2*)(p_s[cur] + (wv * 32 + l16) * 40 + kt * 16 + quad * 4) = w0;
            float f0 = __expf(cc1[kt][0]), f1 = __expf(cc1[kt][1]);
            float f2 = __expf(cc1[kt][2]), f3 = __expf(cc1[kt][3]);
            dacc1 += (f0 + f1) + (f2 + f3);
            uintx2 w1; w1[0] = pack2bf(f0, f1); w1[1] = pack2bf(f2, f3);
            *(uintx2*)(p_s[cur] + (wv * 32 + 16 + l16) * 40 + kt * 16 + quad * 4) = w1;
        }
        __syncthreads();   // B1: P[cur] ready

        if (kc < 31) {
#pragma unroll
            for (int j = 0; j < 4; ++j) {
                *(short8*)(k_s[nxt] + krow * 264 + kseg * 32 + j * 8) = kst[j];
                *(short8*)(v_s[nxt] + t * 40 + j * 8) = vst[j];
            }
        }
        short8 av[4];
#pragma unroll
        for (int fl = 0; fl < 4; ++fl)
            av[fl] = *(const short8*)(v_s[cur] + (wv * 64 + fl * 16 + l16) * 40 + quad * 8);
#pragma unroll
        for (int p2 = 0; p2 < 8; ++p2) {
            short8 bq = *(const short8*)(p_s[cur] + (p2 * 16 + l16) * 40 + quad * 8);
#pragma unroll
            for (int fl = 0; fl < 4; ++fl)
                acc[p2][fl] = __builtin_amdgcn_mfma_f32_16x16x32_bf16(av[fl], bq, acc[p2][fl], 0, 0, 0);
        }
        if (kc < 30) {
            int kp0n = (kc + 2) * 32;
#pragma unroll
            for (int j = 0; j < 4; ++j) {
                kst[j] = *(const short8*)(kbase + (size_t)kp0n * 256 + j * 8);
                vst[j] = *(const short8*)(vbase + kp0n + j * 8);
            }
        }
        __syncthreads();   // B2
    }
    dacc0 += __shfl_xor(dacc0, 16); dacc0 += __shfl_xor(dacc0, 32);
    dacc1 += __shfl_xor(dacc1, 16); dacc1 += __shfl_xor(dacc1, 32);
    if (quad == 0) {
        dsum[wv * 32 + l16] = dacc0;
        dsum[wv * 32 + 16 + l16] = dacc1;
    }
    __syncthreads();
    float* ob = out + (size_t)b * 1048576 + qt * 128;
#pragma unroll
    for (int p2 = 0; p2 < 8; ++p2) {
        float inv = 1.f / dsum[p2 * 16 + l16];
#pragma unroll
        for (int fl = 0; fl < 4; ++fl) {
            int f0 = wv * 64 + fl * 16 + quad * 4;
#pragma unroll
            for (int r = 0; r < 4; ++r)
                ob[(size_t)(f0 + r) * 4096 + p2 * 16 + l16] = acc[p2][fl][r] * inv;
        }
    }
}

extern "C" void kernel_launch(void* const* d_in, const int* in_sizes, int n_in,
                              void* d_out, int out_size, void* d_ws, size_t ws_size,
                              hipStream_t stream) {
    (void)in_sizes; (void)n_in; (void)out_size; (void)ws_size;
    const float* x   = (const float*)d_in[0];
    const float* wqp = (const float*)d_in[1];
    const float* wkv = (const float*)d_in[2];
    float* out = (float*)d_out;

    char* ws = (char*)d_ws;
    short* qraw = (short*)ws;                          // 16 MiB, [b][p][f] normalized bf16
    short* kraw = (short*)(ws + 16777216);             // 4 MiB,  [b][p2][f] normalized bf16
    short* vraw = (short*)(ws + 16777216 + 4194304);   // 4 MiB,  [b][f][p2] bf16

    proj<<<512, 256, 0, stream>>>(x, wqp, wkv, qraw, kraw, vraw);
    attn<<<256, 256, 0, stream>>>(qraw, kraw, vraw, out);
}